// Round 8
// baseline (161.817 us; speedup 1.0000x reference)
//
#include <hip/hip_runtime.h>
#include <hip/hip_fp16.h>
#include <math.h>

#define D 128
#define LN_EPS 1e-5f
#define BKT 64   // slots per destination; deg ~ Poisson(10), P(deg>64) ~ 1e-30

typedef _Float16 f16x8 __attribute__((ext_vector_type(8)));
typedef float    f32x4 __attribute__((ext_vector_type(4)));

// ---------------- prep: W^T -> fp16 (once, 32 KB) + zero degi ----------------
__global__ void prep_kernel(const float* __restrict__ W, _Float16* __restrict__ wtg,
                            int* __restrict__ degi, int N) {
    int idx = blockIdx.x * 256 + threadIdx.x;     // [0, 16384)
    int k = idx >> 7;
    int n = idx & 127;
    wtg[n * D + k] = (_Float16)W[k * D + n];
    for (int i = idx; i < N; i += 64 * 256) degi[i] = 0;
}

// ---------------- fused bucket || gemm: BUCKET BLOCKS FIRST ----------------
// r7 finding: binned CSR != faster; ~500K random slot-claims cost ~30us in any
// formulation (coherence-fabric floor). This round's single variable: grid order.
// Blocks [0,nbB): bucket build (latency-bound, pipes idle) -- resident from t=0.
// Blocks [nbB,..): MFMA GEMM fills the idle compute behind the atomic waves.
// Theory: fused 44.9 ~= gemm(22)+bucket(33)-overlap(10) was phase-serialized by
// dispatch order; swapping gives fused ~= max(33, gemm-throughput) ~= 33-38us.
__global__ void fused_kernel(const float* __restrict__ x, const _Float16* __restrict__ wtg,
                             unsigned* __restrict__ h2,
                             const int* __restrict__ src, const int* __restrict__ dst,
                             int* __restrict__ degi, int* __restrict__ bucket,
                             int N, int E, int nbB) {
    __shared__ _Float16 xs[64][136];
    int tid = threadIdx.x;

    if ((int)blockIdx.x < nbB) {
        int e = blockIdx.x * 256 + tid;
        if (e < E) {
            int d = dst[e];
            int p = atomicAdd(&degi[d], 1);
            if (p < BKT) bucket[(size_t)d * BKT + p] = src[e];
        }
        return;
    }

    int row0 = (blockIdx.x - nbB) * 64;
#pragma unroll
    for (int i = 0; i < 8; ++i) {
        int idx = i * 256 + tid;
        int r   = idx >> 5;
        int c4  = idx & 31;
        float4 v = make_float4(0.f, 0.f, 0.f, 0.f);
        if (row0 + r < N) v = *(const float4*)&x[(size_t)(row0 + r) * D + c4 * 4];
        __half2 lo = __floats2half2_rn(v.x, v.y);
        __half2 hi = __floats2half2_rn(v.z, v.w);
        *(__half2*)&xs[r][c4 * 4]     = lo;
        *(__half2*)&xs[r][c4 * 4 + 2] = hi;
    }
    __syncthreads();

    int l     = tid & 63;
    int mtile = tid >> 6;
    int mn    = l & 15;
    int kq    = (l >> 4) * 8;
    f32x4 acc[8];
#pragma unroll
    for (int nt = 0; nt < 8; ++nt) acc[nt] = (f32x4){0.f, 0.f, 0.f, 0.f};

#pragma unroll
    for (int ks = 0; ks < 4; ++ks) {
        int kb = ks * 32 + kq;
        f16x8 a = *(f16x8*)&xs[mtile * 16 + mn][kb];
#pragma unroll
        for (int nt = 0; nt < 8; ++nt) {
            f16x8 bf = *(const f16x8*)&wtg[(nt * 16 + mn) * D + kb];
            acc[nt] = __builtin_amdgcn_mfma_f32_16x16x32_f16(a, bf, acc[nt], 0, 0, 0);
        }
    }

    int quad = l >> 4;
#pragma unroll
    for (int nt = 0; nt < 8; ++nt) {
#pragma unroll
        for (int rg = 0; rg < 4; ++rg) {
            float v  = acc[nt][rg];
            float pv = __shfl_xor(v, 1);
            if (!(l & 1)) {
                int row = row0 + mtile * 16 + quad * 4 + rg;
                if (row < N) {
                    __half2 p = __floats2half2_rn(v, pv);
                    h2[(size_t)row * (D / 2) + nt * 8 + (mn >> 1)] = *(unsigned*)&p;
                }
            }
        }
    }
}

// ---------------- fused pull-aggregate + bias + LayerNorm + ReLU ----------------
__device__ __forceinline__ void acc_edge(float& a0, float& a1, unsigned u, float w) {
    __half2 hv = *(__half2*)&u;
    a0 = fmaf(__low2float(hv),  w, a0);
    a1 = fmaf(__high2float(hv), w, a1);
}

__global__ void gather_ln_kernel(const int* __restrict__ bucket, const int* __restrict__ degi,
                                 const unsigned* __restrict__ h2, const float* __restrict__ b,
                                 const float* __restrict__ g, const float* __restrict__ be,
                                 float* __restrict__ out, int N) {
    int row  = blockIdx.x * 4 + (threadIdx.x >> 6);
    int lane = threadIdx.x & 63;
    if (row >= N) return;
    int dg   = degi[row];
    int dgc  = dg < BKT ? dg : BKT;
    float di = rsqrtf((float)dg + 1.0f);
    float sw = di * di;
    unsigned su = h2[(size_t)row * (D / 2) + lane];        // self-loop
    float acc0 = 0.f, acc1 = 0.f;
    acc_edge(acc0, acc1, su, sw);
    const int* bk = bucket + (size_t)row * BKT;

    int e = 0;
    for (; e + 8 <= dgc; e += 8) {
        int4 ra = *(const int4*)&bk[e];
        int4 rb = *(const int4*)&bk[e + 4];
        int s[8] = {ra.x, ra.y, ra.z, ra.w, rb.x, rb.y, rb.z, rb.w};
        unsigned u[8]; float wgt[8];
#pragma unroll
        for (int j = 0; j < 8; ++j) u[j] = h2[(size_t)s[j] * (D / 2) + lane];
#pragma unroll
        for (int j = 0; j < 8; ++j) wgt[j] = rsqrtf((float)degi[s[j]] + 1.0f) * di;
#pragma unroll
        for (int j = 0; j < 8; ++j) acc_edge(acc0, acc1, u[j], wgt[j]);
    }
    int rem = dgc - e;
    if (rem & 4) {
        int4 ra = *(const int4*)&bk[e];
        int s[4] = {ra.x, ra.y, ra.z, ra.w};
        unsigned u[4]; float wgt[4];
#pragma unroll
        for (int j = 0; j < 4; ++j) u[j] = h2[(size_t)s[j] * (D / 2) + lane];
#pragma unroll
        for (int j = 0; j < 4; ++j) wgt[j] = rsqrtf((float)degi[s[j]] + 1.0f) * di;
#pragma unroll
        for (int j = 0; j < 4; ++j) acc_edge(acc0, acc1, u[j], wgt[j]);
        e += 4;
    }
    if (rem & 2) {
        int s0 = bk[e], s1 = bk[e + 1];
        unsigned u0 = h2[(size_t)s0 * (D / 2) + lane];
        unsigned u1 = h2[(size_t)s1 * (D / 2) + lane];
        float w0 = rsqrtf((float)degi[s0] + 1.0f) * di;
        float w1 = rsqrtf((float)degi[s1] + 1.0f) * di;
        acc_edge(acc0, acc1, u0, w0);
        acc_edge(acc0, acc1, u1, w1);
        e += 2;
    }
    if (rem & 1) {
        int s0 = bk[e];
        unsigned u0 = h2[(size_t)s0 * (D / 2) + lane];
        float w0 = rsqrtf((float)degi[s0] + 1.0f) * di;
        acc_edge(acc0, acc1, u0, w0);
    }

    float2 bb = *(const float2*)&b[lane * 2];
    float v0 = acc0 + bb.x;
    float v1 = acc1 + bb.y;
    float s = v0 + v1;
    float q = v0 * v0 + v1 * v1;
#pragma unroll
    for (int off = 32; off; off >>= 1) {
        s += __shfl_xor(s, off);
        q += __shfl_xor(q, off);
    }
    float mean = s * (1.0f / 128.0f);
    float var  = q * (1.0f / 128.0f) - mean * mean;
    float rstd = rsqrtf(var + LN_EPS);
    float2 gg = *(const float2*)&g[lane * 2];
    float2 eb = *(const float2*)&be[lane * 2];
    float y0 = (v0 - mean) * rstd * gg.x + eb.x;
    float y1 = (v1 - mean) * rstd * gg.y + eb.y;
    *(float2*)&out[(size_t)row * D + lane * 2] = make_float2(fmaxf(y0, 0.0f), fmaxf(y1, 0.0f));
}

extern "C" void kernel_launch(void* const* d_in, const int* in_sizes, int n_in,
                              void* d_out, int out_size, void* d_ws, size_t ws_size,
                              hipStream_t stream) {
    const float* x  = (const float*)d_in[0];
    const int*   ei = (const int*)d_in[1];
    const float* W  = (const float*)d_in[2];
    const float* b  = (const float*)d_in[3];
    const float* g  = (const float*)d_in[4];
    const float* be = (const float*)d_in[5];

    int N = in_sizes[0] / D;
    int E = in_sizes[1] / 2;
    const int* src = ei;
    const int* dst = ei + E;

    float* out = (float*)d_out;

    char* w = (char*)d_ws;
    unsigned* h2    = (unsigned*)w;           w += (size_t)N * (D / 2) * sizeof(unsigned);
    int*      degi  = (int*)w;                w += (size_t)N * sizeof(int);
    _Float16* wtg   = (_Float16*)w;           w += (size_t)D * D * sizeof(_Float16);
    int*      bucket= (int*)w;                w += (size_t)N * BKT * sizeof(int);

    int nbG = (N + 63) / 64;
    int nbB = (E + 255) / 256;

    prep_kernel <<<64,        256, 0, stream>>>(W, wtg, degi, N);
    fused_kernel<<<nbB + nbG, 256, 0, stream>>>(x, wtg, h2, src, dst, degi, bucket,
                                                N, E, nbB);
    gather_ln_kernel<<<(N + 3) / 4, 256, 0, stream>>>(bucket, degi, h2,
                                                      b, g, be, out, N);
}

// Round 9
// 147.746 us; speedup vs baseline: 1.0952x; 1.0952x over previous
//
#include <hip/hip_runtime.h>
#include <hip/hip_fp16.h>
#include <math.h>

#define D 128
#define LN_EPS 1e-5f
#define BKT 64   // slots per destination; deg ~ Poisson(10), P(deg>64) ~ 1e-30

typedef _Float16 f16x8 __attribute__((ext_vector_type(8)));
typedef float    f32x4 __attribute__((ext_vector_type(4)));

// ---------------- prep: W^T -> fp16 (once, 32 KB) + zero degi ----------------
__global__ void prep_kernel(const float* __restrict__ W, _Float16* __restrict__ wtg,
                            int* __restrict__ degi, int N) {
    int idx = blockIdx.x * 256 + threadIdx.x;     // [0, 16384)
    int k = idx >> 7;
    int n = idx & 127;
    wtg[n * D + k] = (_Float16)W[k * D + n];
    for (int i = idx; i < N; i += 64 * 256) degi[i] = 0;
}

// ---------------- fused gemm || bucket (r0 exact: best-known 44.9us config) ----------------
__global__ void fused_kernel(const float* __restrict__ x, const _Float16* __restrict__ wtg,
                             unsigned* __restrict__ h2,
                             const int* __restrict__ src, const int* __restrict__ dst,
                             int* __restrict__ degi, int* __restrict__ bucket,
                             int N, int E, int nbG) {
    __shared__ _Float16 xs[64][136];
    int tid = threadIdx.x;

    if ((int)blockIdx.x >= nbG) {
        int e = (blockIdx.x - nbG) * 256 + tid;
        if (e < E) {
            int d = dst[e];
            int p = atomicAdd(&degi[d], 1);
            if (p < BKT) bucket[(size_t)d * BKT + p] = src[e];
        }
        return;
    }

    int row0 = blockIdx.x * 64;
#pragma unroll
    for (int i = 0; i < 8; ++i) {
        int idx = i * 256 + tid;
        int r   = idx >> 5;
        int c4  = idx & 31;
        float4 v = make_float4(0.f, 0.f, 0.f, 0.f);
        if (row0 + r < N) v = *(const float4*)&x[(size_t)(row0 + r) * D + c4 * 4];
        __half2 lo = __floats2half2_rn(v.x, v.y);
        __half2 hi = __floats2half2_rn(v.z, v.w);
        *(__half2*)&xs[r][c4 * 4]     = lo;
        *(__half2*)&xs[r][c4 * 4 + 2] = hi;
    }
    __syncthreads();

    int l     = tid & 63;
    int mtile = tid >> 6;
    int mn    = l & 15;
    int kq    = (l >> 4) * 8;
    f32x4 acc[8];
#pragma unroll
    for (int nt = 0; nt < 8; ++nt) acc[nt] = (f32x4){0.f, 0.f, 0.f, 0.f};

#pragma unroll
    for (int ks = 0; ks < 4; ++ks) {
        int kb = ks * 32 + kq;
        f16x8 a = *(f16x8*)&xs[mtile * 16 + mn][kb];
#pragma unroll
        for (int nt = 0; nt < 8; ++nt) {
            f16x8 bf = *(const f16x8*)&wtg[(nt * 16 + mn) * D + kb];
            acc[nt] = __builtin_amdgcn_mfma_f32_16x16x32_f16(a, bf, acc[nt], 0, 0, 0);
        }
    }

    int quad = l >> 4;
#pragma unroll
    for (int nt = 0; nt < 8; ++nt) {
#pragma unroll
        for (int rg = 0; rg < 4; ++rg) {
            float v  = acc[nt][rg];
            float pv = __shfl_xor(v, 1);
            if (!(l & 1)) {
                int row = row0 + mtile * 16 + quad * 4 + rg;
                if (row < N) {
                    __half2 p = __floats2half2_rn(v, pv);
                    h2[(size_t)row * (D / 2) + nt * 8 + (mn >> 1)] = *(unsigned*)&p;
                }
            }
        }
    }
}

// ---------------- fused pull-aggregate + bias + LayerNorm + ReLU ----------------
// TWO edges per gather instruction: lanes 0-31 = even edges, lanes 32-63 = odd
// edges; each lane loads uint2 (4 fp16 feats) of its half's source row. Halves
// accumulate independent partial sums (4 feats/lane); one shfl_xor(32) combine
// at the end. Same bytes as r0, ~half the VMEM gather instructions.
// (Experiment: discriminates issue/latency-bound (30->~20us) vs BW-bound (null).)
__device__ __forceinline__ void acc4(float& a0, float& a1, float& a2, float& a3,
                                     uint2 u, float w) {
    __half2 h01 = *(__half2*)&u.x;
    __half2 h23 = *(__half2*)&u.y;
    a0 = fmaf(__low2float(h01),  w, a0);
    a1 = fmaf(__high2float(h01), w, a1);
    a2 = fmaf(__low2float(h23),  w, a2);
    a3 = fmaf(__high2float(h23), w, a3);
}

__global__ void gather_ln_kernel(const int* __restrict__ bucket, const int* __restrict__ degi,
                                 const unsigned* __restrict__ h2, const float* __restrict__ b,
                                 const float* __restrict__ g, const float* __restrict__ be,
                                 float* __restrict__ out, int N) {
    int row  = blockIdx.x * 4 + (threadIdx.x >> 6);
    int lane = threadIdx.x & 63;
    if (row >= N) return;
    int half = lane >> 5;        // 0: even-indexed edges, 1: odd-indexed edges
    int c    = lane & 31;        // feature quad: features [4c, 4c+4)
    int dg   = degi[row];
    int dgc  = dg < BKT ? dg : BKT;
    float di = rsqrtf((float)dg + 1.0f);
    float sw = di * di;
    float a0 = 0.f, a1 = 0.f, a2 = 0.f, a3 = 0.f;

    // self-loop: both halves read (broadcast), only low half accumulates
    uint2 su = *(const uint2*)&h2[(size_t)row * (D / 2) + c * 2];
    if (half == 0) acc4(a0, a1, a2, a3, su, sw);

    const int* bk = bucket + (size_t)row * BKT;
    int e = 0;
    for (; e + 8 <= dgc; e += 8) {
        int4 ra = *(const int4*)&bk[e];
        int4 rb = *(const int4*)&bk[e + 4];
        int sj[4];
        sj[0] = half ? ra.y : ra.x;
        sj[1] = half ? ra.w : ra.z;
        sj[2] = half ? rb.y : rb.x;
        sj[3] = half ? rb.w : rb.z;
        uint2 u[4]; float wgt[4];
#pragma unroll
        for (int j = 0; j < 4; ++j) u[j] = *(const uint2*)&h2[(size_t)sj[j] * (D / 2) + c * 2];
#pragma unroll
        for (int j = 0; j < 4; ++j) wgt[j] = rsqrtf((float)degi[sj[j]] + 1.0f) * di;
#pragma unroll
        for (int j = 0; j < 4; ++j) acc4(a0, a1, a2, a3, u[j], wgt[j]);
    }
    int rem = dgc - e;
    if (rem & 4) {
        int4 ra = *(const int4*)&bk[e];
        int sj0 = half ? ra.y : ra.x;
        int sj1 = half ? ra.w : ra.z;
        uint2 u0 = *(const uint2*)&h2[(size_t)sj0 * (D / 2) + c * 2];
        uint2 u1 = *(const uint2*)&h2[(size_t)sj1 * (D / 2) + c * 2];
        float w0 = rsqrtf((float)degi[sj0] + 1.0f) * di;
        float w1 = rsqrtf((float)degi[sj1] + 1.0f) * di;
        acc4(a0, a1, a2, a3, u0, w0);
        acc4(a0, a1, a2, a3, u1, w1);
        e += 4;
    }
    if (rem & 2) {
        int s0 = bk[e], s1 = bk[e + 1];
        int sj = half ? s1 : s0;
        uint2 u0 = *(const uint2*)&h2[(size_t)sj * (D / 2) + c * 2];
        float w0 = rsqrtf((float)degi[sj] + 1.0f) * di;
        acc4(a0, a1, a2, a3, u0, w0);
        e += 2;
    }
    if (rem & 1) {
        int s0 = bk[e];
        uint2 u0 = *(const uint2*)&h2[(size_t)s0 * (D / 2) + c * 2];
        float w0 = rsqrtf((float)degi[s0] + 1.0f) * di;
        if (half == 0) acc4(a0, a1, a2, a3, u0, w0);
    }

    // combine the two half-wave partial sums
    a0 += __shfl_xor(a0, 32);
    a1 += __shfl_xor(a1, 32);
    a2 += __shfl_xor(a2, 32);
    a3 += __shfl_xor(a3, 32);

    float4 bb = *(const float4*)&b[c * 4];
    float v0 = a0 + bb.x;
    float v1 = a1 + bb.y;
    float v2 = a2 + bb.z;
    float v3 = a3 + bb.w;
    float s = v0 + v1 + v2 + v3;
    float q = v0 * v0 + v1 * v1 + v2 * v2 + v3 * v3;
#pragma unroll
    for (int off = 16; off; off >>= 1) {
        s += __shfl_xor(s, off);
        q += __shfl_xor(q, off);
    }
    float mean = s * (1.0f / 128.0f);
    float var  = q * (1.0f / 128.0f) - mean * mean;
    float rstd = rsqrtf(var + LN_EPS);
    float4 gg = *(const float4*)&g[c * 4];
    float4 eb = *(const float4*)&be[c * 4];
    float y0 = fmaxf((v0 - mean) * rstd * gg.x + eb.x, 0.0f);
    float y1 = fmaxf((v1 - mean) * rstd * gg.y + eb.y, 0.0f);
    float y2 = fmaxf((v2 - mean) * rstd * gg.z + eb.z, 0.0f);
    float y3 = fmaxf((v3 - mean) * rstd * gg.w + eb.w, 0.0f);
    if (half == 0)
        *(float4*)&out[(size_t)row * D + c * 4] = make_float4(y0, y1, y2, y3);
}

extern "C" void kernel_launch(void* const* d_in, const int* in_sizes, int n_in,
                              void* d_out, int out_size, void* d_ws, size_t ws_size,
                              hipStream_t stream) {
    const float* x  = (const float*)d_in[0];
    const int*   ei = (const int*)d_in[1];
    const float* W  = (const float*)d_in[2];
    const float* b  = (const float*)d_in[3];
    const float* g  = (const float*)d_in[4];
    const float* be = (const float*)d_in[5];

    int N = in_sizes[0] / D;
    int E = in_sizes[1] / 2;
    const int* src = ei;
    const int* dst = ei + E;

    float* out = (float*)d_out;

    char* w = (char*)d_ws;
    unsigned* h2    = (unsigned*)w;           w += (size_t)N * (D / 2) * sizeof(unsigned);
    int*      degi  = (int*)w;                w += (size_t)N * sizeof(int);
    _Float16* wtg   = (_Float16*)w;           w += (size_t)D * D * sizeof(_Float16);
    int*      bucket= (int*)w;                w += (size_t)N * BKT * sizeof(int);

    int nbG = (N + 63) / 64;
    int nbB = (E + 255) / 256;

    prep_kernel <<<64,        256, 0, stream>>>(W, wtg, degi, N);
    fused_kernel<<<nbG + nbB, 256, 0, stream>>>(x, wtg, h2, src, dst, degi, bucket,
                                                N, E, nbG);
    gather_ln_kernel<<<(N + 3) / 4, 256, 0, stream>>>(bucket, degi, h2,
                                                      b, g, be, out, N);
}